// Round 6
// baseline (13052.814 us; speedup 1.0000x reference)
//
#include <hip/hip_runtime.h>
#include <hip/hip_bf16.h>
#include <math.h>

#define BB 256
#define TT 256
#define INW 256
#define HH 1024
#define LL 8
#define CSW 10
#define OUTW 64
#define GG 4112
#define KH 1024            // sequential GEMM K (h only)
#define KXP 896            // x-part GEMM K: 3*288 = 864 padded to 14*64
#define NPAD 4224          // 4112 padded to 33*128
#define BH (BB * HH)
#define NPANEL 66          // 33 Whi + 33 Wlo panels

typedef __attribute__((ext_vector_type(8))) short short8;
typedef __attribute__((ext_vector_type(4))) float f32x4;

__device__ __forceinline__ float bf2f(ushort u) {
    union { float f; unsigned int i; } v; v.i = ((unsigned int)u) << 16; return v.f;
}
__device__ __forceinline__ ushort f2bf(float f) {
    __hip_bfloat16 h = __float2bfloat16(f);
    return *(ushort*)&h;
}
__device__ __forceinline__ float sigf(float v) { return 1.0f / (1.0f + expf(-v)); }

// ================= generic bf16 MFMA GEMM, reg-prefetch double-buffered ==========
// C(MxN) = epilogue(A(MxK)*B(KxN) + bias);  B passed TRANSPOSED: BT[N][K].
// AMODE 0: plain bf16 A (rows contiguous at ldaA)
// AMODE 1: recurrent h-gather at step t (K=1024, branch-free). Panel-pinned:
//          panel p<33: Whi N-tile p (members z0,z2 x by); p>=33: Wlo (z1 x by).
//          z0: hHi x Whi   z1: hHi x Wlo   z2: hLo x Whi.  XCD = p%8.
// AMODE 2: conv gather: A[m][k=ks*1024+c] = hR[(tBase+tt+ks)%RING][b][c]*ldw[m][ks]
//          1-D m-tile-pinned grid: bx=(vid>>3)&7, mtile=(vid>>6)*8+(vid&7), nM in `t`
// EPI 0: fp32 partial store at zSel*splitStride (no bias)
// EPI 1: relu->bf16  2: sigmoid->bf16  3: rnn=TH*(v+bias)+h_t->bf16  4: out sigmoid fp32
template<int WR, int WC, int AMODE, int EPI>
__global__ __launch_bounds__(WR * WC * 64) void mm_kernel(
    const ushort* __restrict__ A, const ushort* __restrict__ hR,
    const ushort* __restrict__ hLo,
    const ushort* __restrict__ BT, const float* __restrict__ bias,
    void* __restrict__ Cp, const float* __restrict__ ldw,
    const ushort* __restrict__ TH, float* __restrict__ outp,
    int splitStride, int ldaA, int ldb, int ldc, int K, int t, int RING, int tBase)
{
    constexpr int BM = WR * 64, BN = WC * 64, NT = WR * WC * 64, LS = 72;
    constexpr int AIT = BM * 8 / NT, BIT = BN * 8 / NT;
    __shared__ ushort As[BM * LS];
    __shared__ ushort Bs[BN * LS];
    const int tid = threadIdx.x;
    const int lane = tid & 63, wave = tid >> 6;
    const int wr = wave / WC, wc = wave % WC;

    int bx, by, zSel = 0;
    const ushort* BTeff = BT;
    const ushort* Abase = A;
    if (AMODE == 1) {
        int vid = blockIdx.x;
        int xcd = vid & 7, q = vid >> 3;
        int p = -1, mem = 0;
        for (int j = 0; ; ++j) {
            int pp = xcd + 8 * j;
            if (pp >= NPANEL) break;
            int cc = (pp < 33) ? 4 : 2;
            if (q < cc) { p = pp; mem = q; break; }
            q -= cc;
        }
        if (p < 0) return;
        if (p < 33) { bx = p;      zSel = (mem < 2) ? 0 : 2; by = mem & 1; BTeff = BT; }
        else        { bx = p - 33; zSel = 1;                 by = mem & 1; BTeff = A;  }
        Abase = (zSel == 2) ? hLo : hR + (size_t)((t + 8) % RING) * BH;
    } else if (AMODE == 2) {
        int vid = blockIdx.x;
        bx = (vid >> 3) & 7;
        by = ((vid >> 6) << 3) + (vid & 7);
        if (by >= t) return;        // t carries nM
    } else {
        bx = blockIdx.x; by = blockIdx.y;
    }
    const int m0 = by * BM, n0 = bx * BN;
    f32x4 acc[4][4] = {};

    auto gather = [&](int ktl, short8* vA, short8* vB) {
#pragma unroll
        for (int i = 0; i < AIT; ++i) {
            int id = tid + i * NT;
            int r = id >> 3, cc = id & 7;
            int k = ktl + cc * 8;
            short8 v;
            if (AMODE == 0) {
                v = *(const short8*)(A + (size_t)(m0 + r) * ldaA + k);
            } else if (AMODE == 1) {
                v = *(const short8*)(Abase + (size_t)(m0 + r) * HH + k);
            } else {  // conv gather
                int ks = k >> 10, c = k & 1023;
                int tt = m0 >> 8, b = (m0 & 255) + r;
                int slot = (tBase + tt + ks) % RING;
                short8 hv = *(const short8*)(hR + (size_t)slot * BH + (size_t)b * HH + c);
                float s = ldw[((size_t)tt * 256 + b) * CSW + ks];
                ushort* pv = (ushort*)&hv;
                ushort* po = (ushort*)&v;
#pragma unroll
                for (int j = 0; j < 8; ++j) po[j] = f2bf(bf2f(pv[j]) * s);
            }
            vA[i] = v;
        }
#pragma unroll
        for (int i = 0; i < BIT; ++i) {
            int id = tid + i * NT;
            int n = id >> 3, cc = id & 7;
            vB[i] = *(const short8*)(BTeff + (size_t)(n0 + n) * ldb + ktl + cc * 8);
        }
    };

    short8 vA[AIT], vB[BIT];
    gather(0, vA, vB);

    for (int kt = 0; kt < K; kt += 64) {
#pragma unroll
        for (int i = 0; i < AIT; ++i) {
            int id = tid + i * NT;
            *(short8*)(As + (id >> 3) * LS + (id & 7) * 8) = vA[i];
        }
#pragma unroll
        for (int i = 0; i < BIT; ++i) {
            int id = tid + i * NT;
            *(short8*)(Bs + (id >> 3) * LS + (id & 7) * 8) = vB[i];
        }
        __syncthreads();
        if (kt + 64 < K) gather(kt + 64, vA, vB);   // prefetch next tile
#pragma unroll
        for (int kf = 0; kf < 2; ++kf) {
            short8 aF[4], bF[4];
#pragma unroll
            for (int mi = 0; mi < 4; ++mi)
                aF[mi] = *(const short8*)(As + (wr * 64 + mi * 16 + (lane & 15)) * LS + kf * 32 + (lane >> 4) * 8);
#pragma unroll
            for (int ni = 0; ni < 4; ++ni)
                bF[ni] = *(const short8*)(Bs + (wc * 64 + ni * 16 + (lane & 15)) * LS + kf * 32 + (lane >> 4) * 8);
#pragma unroll
            for (int mi = 0; mi < 4; ++mi)
#pragma unroll
                for (int ni = 0; ni < 4; ++ni)
                    acc[mi][ni] = __builtin_amdgcn_mfma_f32_16x16x32_bf16(aF[mi], bF[ni], acc[mi][ni], 0, 0, 0);
        }
        __syncthreads();
    }
#pragma unroll
    for (int mi = 0; mi < 4; ++mi) {
#pragma unroll
        for (int ni = 0; ni < 4; ++ni) {
#pragma unroll
            for (int j = 0; j < 4; ++j) {
                int row = m0 + wr * 64 + mi * 16 + ((lane >> 4) << 2) + j;
                int col = n0 + wc * 64 + ni * 16 + (lane & 15);
                float v = acc[mi][ni][j];
                if (EPI != 0 && bias) v += bias[col];
                if (EPI == 0) {
                    ((float*)Cp)[(size_t)zSel * splitStride + (size_t)row * ldc + col] = v;
                } else if (EPI == 1) {
                    ((ushort*)Cp)[(size_t)row * ldc + col] = f2bf(v > 0.f ? v : 0.f);
                } else if (EPI == 2) {
                    ((ushort*)Cp)[(size_t)row * ldc + col] = f2bf(sigf(v));
                } else if (EPI == 3) {
                    int tt = row >> 8, b = row & 255;
                    int slot = (tBase + tt + 9) % RING;
                    float th = bf2f(TH[(size_t)row * HH + col]);
                    float h  = bf2f(hR[(size_t)slot * BH + (size_t)b * HH + col]);
                    ((ushort*)Cp)[(size_t)row * ldc + col] = f2bf(th * v + h);
                } else {
                    int tt = tBase + (row >> 8), b = row & 255;
                    outp[((size_t)b * TT + tt) * OUTW + col] = sigf(v);
                }
            }
        }
    }
}

// ================= weight prep =================
// h-part weights: WhiT/WloT [NPAD][KH], w = rec_w[k][n]
__global__ void build_whl(const float* __restrict__ rw,
                          ushort* __restrict__ WhiT, ushort* __restrict__ WloT)
{
    size_t i = (size_t)blockIdx.x * 256 + threadIdx.x;
    if (i >= (size_t)NPAD * KH) return;
    int n = (int)(i / KH), k = (int)(i % KH);
    float w = (n < GG) ? rw[(size_t)k * GG + n] : 0.f;
    ushort hi = f2bf(w);
    WhiT[i] = hi;
    WloT[i] = f2bf(w - bf2f(hi));
}

// x-part weights: WxT [NPAD][KXP]; seg0 hi, seg1 lo, seg2 hi of
// w(kk,n): kk<256: kw[kk][n]; kk==256: kw[256][n]; kk==257: rw[1024][n]
__global__ void build_wxt(const float* __restrict__ kw, const float* __restrict__ rw,
                          ushort* __restrict__ WxT)
{
    size_t i = (size_t)blockIdx.x * 256 + threadIdx.x;
    if (i >= (size_t)NPAD * KXP) return;
    int n = (int)(i / KXP), k = (int)(i % KXP);
    int seg = k / 288, kk = k - seg * 288;
    float w = 0.f;
    if (n < GG && seg < 3) {
        if (kk < 256)      w = kw[(size_t)kk * GG + n];
        else if (kk == 256) w = kw[(size_t)256 * GG + n];
        else if (kk == 257) w = rw[(size_t)1024 * GG + n];
    }
    ushort hi = f2bf(w);
    WxT[i] = (seg == 1) ? f2bf(w - bf2f(hi)) : hi;
}

__global__ void build_bc(const float* __restrict__ kb, const float* __restrict__ rb,
                         float* __restrict__ bc)
{
    int i = blockIdx.x * 256 + threadIdx.x;
    if (i < NPAD) bc[i] = (i < GG) ? kb[i] + rb[i] : 0.f;
}

// per-chunk A for x-GEMM: XAc[m][k], m = tLocal*256+b; seg0/1 hi, seg2 lo
__global__ void build_xac(const float* __restrict__ x, const float* __restrict__ tim,
                          ushort* __restrict__ XAc, int tBase, int Mloc)
{
    size_t i = (size_t)blockIdx.x * 256 + threadIdx.x;
    if (i >= (size_t)Mloc * KXP) return;
    int m = (int)(i / KXP), k = (int)(i % KXP);
    int t = tBase + (m >> 8), b = m & 255;
    int seg = k / 288, kk = k - seg * 288;
    float v = 0.f;
    if (seg < 3) {
        if (kk < 256)       v = x[((size_t)b * TT + t) * INW + kk];
        else if (kk < 258)  v = tim[(size_t)b * TT + t];
    }
    ushort hi = f2bf(v);
    XAc[i] = (seg == 2) ? f2bf(v - bf2f(hi)) : hi;
}

__global__ void build_ctt(const float* __restrict__ cw, ushort* __restrict__ ctT)
{
    size_t i = (size_t)blockIdx.x * 256 + threadIdx.x;
    if (i >= (size_t)HH * HH * CSW) return;
    int o = (int)(i / (HH * CSW)), rest = (int)(i % (HH * CSW));
    int k = rest >> 10, c = rest & 1023;
    ctT[i] = f2bf(cw[((size_t)o * HH + c) * CSW + k]);
}

__global__ void build_swt(const float* __restrict__ sw, const float* __restrict__ sb,
                          ushort* __restrict__ swT, float* __restrict__ sbP)
{
    int i = blockIdx.x * 256 + threadIdx.x;
    if (i < 256 * 1024) {
        int n = i >> 10, k = i & 1023;
        swT[i] = f2bf(n < 170 ? sw[(size_t)k * 170 + n] : 0.f);
    }
    if (i < 256) sbP[i] = (i < 170) ? sb[i] : 0.f;
}

__global__ void build_rswt(const float* __restrict__ rsw, ushort* __restrict__ rswT)
{
    int i = blockIdx.x * 256 + threadIdx.x;
    if (i >= 1024 * 256) return;
    int n = i >> 8, k = i & 255;
    rswT[i] = f2bf(k < 170 ? rsw[(size_t)k * HH + n] : 0.f);
}

__global__ void build_owt(const float* __restrict__ ow, ushort* __restrict__ owT)
{
    int i = blockIdx.x * 256 + threadIdx.x;
    if (i >= OUTW * HH) return;
    int n = i >> 10, k = i & 1023;
    owT[i] = f2bf(ow[(size_t)k * OUTW + n]);
}

// ================= per-step pointwise: xo = z0+z1+z2 + xo_x + bc ============
__global__ __launch_bounds__(256) void step_kernel(
    const float* __restrict__ xoP, const float* __restrict__ xoX,
    const float* __restrict__ bc,
    float* __restrict__ c, ushort* __restrict__ hR, ushort* __restrict__ hLo,
    float* __restrict__ dist, int t, int tBase, int RING)
{
    const size_t S = (size_t)BB * NPAD;
    int b = blockIdx.x, tid = threadIdx.x;
    const float* x0 = xoP + (size_t)b * NPAD;
    const float* xx = xoX + ((size_t)(t - tBase) * 256 + b) * NPAD;
    __shared__ float fm[LL], im[LL];
    if (tid == 0) {
        float xr[2 * LL];
        for (int l = 0; l < 2 * LL; ++l)
            xr[l] = x0[l] + x0[S + l] + x0[2 * S + l] + xx[l] + bc[l];
        float m1 = -1e30f, m2 = -1e30f;
        for (int l = 0; l < LL; ++l) { m1 = fmaxf(m1, xr[l]); m2 = fmaxf(m2, xr[LL + l]); }
        float e1[LL], e2[LL], s1 = 0.f, s2 = 0.f;
        for (int l = 0; l < LL; ++l) {
            e1[l] = expf(xr[l] - m1); s1 += e1[l];
            e2[l] = expf(xr[LL + l] - m2); s2 += e2[l];
        }
        float cum = 0.f, mean = 0.f;
        for (int l = 0; l < LL; ++l) { cum += e1[l] / s1; fm[l] = cum; mean += cum; }
        float rc = 0.f;
        for (int l = LL - 1; l >= 0; --l) { rc += e2[l] / s2; im[l] = rc; }
        dist[(size_t)t * BB + b] = 1.0f - mean / LL;
    }
    __syncthreads();
    int slot = (t + 9) % RING;
    for (int e = tid; e < HH; e += 256) {
        int l = e >> 7;
        int c0 = 2 * LL + e;
        float f  = sigf(x0[c0] + x0[S + c0] + x0[2 * S + c0] + xx[c0] + bc[c0]);
        int c1 = c0 + HH;
        float ig = sigf(x0[c1] + x0[S + c1] + x0[2 * S + c1] + xx[c1] + bc[c1]);
        int c2 = c1 + HH;
        float og = sigf(x0[c2] + x0[S + c2] + x0[2 * S + c2] + xx[c2] + bc[c2]);
        int c3 = c2 + HH;
        float ci = tanhf(x0[c3] + x0[S + c3] + x0[2 * S + c3] + xx[c3] + bc[c3]);
        size_t idx = (size_t)b * HH + e;
        float cl = c[idx];
        float F = fm[l], I = im[l], OV = F * I;
        float cn = OV * (f * cl + ig * ci) + (F - OV) * cl + (I - OV) * ci;
        float hn = og * tanhf(cn);
        c[idx] = cn;
        ushort hi = f2bf(hn);
        hR[(size_t)slot * BH + idx] = hi;
        hLo[idx] = f2bf(hn - bf2f(hi));
    }
}

// ================= chunk helpers =================
__global__ void ld_chunk_kernel(const float* __restrict__ dist, float* __restrict__ ldC,
                                int tBase, int Mloc)
{
    int id = blockIdx.x * 256 + threadIdx.x;
    if (id >= Mloc) return;
    int t = tBase + (id >> 8), b = id & 255;
    float cv[CSW], cum = 0.f, mx = -1e30f;
#pragma unroll
    for (int k = 0; k < CSW; ++k) {
        int ts = t - 9 + k;
        cum += (ts >= 0) ? dist[(size_t)ts * BB + b] : 0.f;
        cv[k] = cum; mx = fmaxf(mx, cum);
    }
    float ss = 0.f;
#pragma unroll
    for (int k = 0; k < CSW; ++k) { cv[k] = expf(cv[k] - mx); ss += cv[k]; }
    float inv = 1.0f / ss;
#pragma unroll
    for (int k = 0; k < CSW; ++k) ldC[(size_t)id * CSW + k] = cv[k] * inv;
}

__global__ void mlh_kernel(const ushort* __restrict__ hR, const float* __restrict__ ldC,
                           ushort* __restrict__ MLH, int tBase, int RING)
{
    size_t id = (size_t)blockIdx.x * 256 + threadIdx.x;
    int m = (int)(id >> 7);
    int c0 = ((int)(id & 127)) << 3;
    int t = tBase + (m >> 8), b = m & 255;
    float acc[8] = {};
#pragma unroll
    for (int k = 0; k < CSW; ++k) {
        float s = ldC[(size_t)m * CSW + k];
        int slot = (t + k) % RING;
        short8 hv = *(const short8*)(hR + (size_t)slot * BH + (size_t)b * HH + c0);
        ushort* pv = (ushort*)&hv;
#pragma unroll
        for (int j = 0; j < 8; ++j) acc[j] += bf2f(pv[j]) * s;
    }
#pragma unroll
    for (int j = 0; j < 8; ++j) MLH[(size_t)m * HH + c0 + j] = f2bf(acc[j] * 0.1f);
}

// ================= launch =================
extern "C" void kernel_launch(void* const* d_in, const int* in_sizes, int n_in,
                              void* d_out, int out_size, void* d_ws, size_t ws_size,
                              hipStream_t stream)
{
    const float* x   = (const float*)d_in[0];
    const float* tim = (const float*)d_in[1];
    const float* kw  = (const float*)d_in[2];
    const float* kb  = (const float*)d_in[3];
    const float* rw  = (const float*)d_in[4];
    const float* rb  = (const float*)d_in[5];
    const float* sw  = (const float*)d_in[6];
    const float* sb  = (const float*)d_in[7];
    const float* rsw = (const float*)d_in[8];
    const float* rsb = (const float*)d_in[9];
    const float* cw  = (const float*)d_in[10];
    const float* cb  = (const float*)d_in[11];
    const float* ow  = (const float*)d_in[12];
    const float* ob  = (const float*)d_in[13];
    float* out  = (float*)d_out;
    float* dist = out + (size_t)BB * TT * OUTW;

    auto planSize = [&](int tch) -> size_t {
        size_t o = 0;
        auto al = [&](size_t bytes) { o += (bytes + 255) & ~(size_t)255; };
        int ring = tch + 9;
        al((size_t)ring * BH * 2);             // hRing
        al((size_t)BH * 2);                    // hLo
        al((size_t)BH * 4);                    // c
        al((size_t)NPAD * KH * 2);             // WhiT
        al((size_t)NPAD * KH * 2);             // WloT
        al((size_t)NPAD * KXP * 2);            // WxT
        al((size_t)NPAD * 4);                  // bc
        al((size_t)3 * BB * NPAD * 4);         // xoP
        al((size_t)tch * 256 * NPAD * 4);      // xo_x
        al((size_t)tch * 256 * KXP * 2);       // XAc
        al((size_t)tch * 256 * CSW * 4);       // ldC
        al((size_t)HH * HH * CSW * 2);         // ctT
        al((size_t)256 * 1024 * 2);            // swT
        al((size_t)256 * 4);                   // sbP
        al((size_t)1024 * 256 * 2);            // rswT
        al((size_t)OUTW * HH * 2);             // owT
        al((size_t)tch * 256 * HH * 2);        // MLH / RNN
        al((size_t)tch * 256 * 256 * 2);       // TH1
        al((size_t)tch * 256 * HH * 2);        // TH
        return o;
    };
    const int cands[5] = {32, 16, 8, 4, 2};
    int TCH = 0;
    for (int ci = 0; ci < 5; ++ci)
        if (planSize(cands[ci]) <= ws_size) { TCH = cands[ci]; break; }
    if (TCH == 0) return;   // diagnostic: output stays zero -> absmax ~0.83
    const int RING = TCH + 9;
    const int Mloc = TCH * 256;
    const int nM = Mloc / 128;

    char* base = (char*)d_ws;
    size_t off = 0;
    auto alloc = [&](size_t bytes) { char* p = base + off; off += (bytes + 255) & ~(size_t)255; return p; };
    ushort* hRing = (ushort*)alloc((size_t)RING * BH * 2);
    ushort* hLo   = (ushort*)alloc((size_t)BH * 2);
    float*  c     = (float*) alloc((size_t)BH * 4);
    ushort* WhiT  = (ushort*)alloc((size_t)NPAD * KH * 2);
    ushort* WloT  = (ushort*)alloc((size_t)NPAD * KH * 2);
    ushort* WxT   = (ushort*)alloc((size_t)NPAD * KXP * 2);
    float*  bc    = (float*) alloc((size_t)NPAD * 4);
    float*  xoP   = (float*) alloc((size_t)3 * BB * NPAD * 4);
    float*  xoX   = (float*) alloc((size_t)Mloc * NPAD * 4);
    ushort* XAc   = (ushort*)alloc((size_t)Mloc * KXP * 2);
    float*  ldC   = (float*) alloc((size_t)Mloc * CSW * 4);
    ushort* ctT   = (ushort*)alloc((size_t)HH * HH * CSW * 2);
    ushort* swT   = (ushort*)alloc((size_t)256 * 1024 * 2);
    float*  sbP   = (float*) alloc((size_t)256 * 4);
    ushort* rswT  = (ushort*)alloc((size_t)1024 * 256 * 2);
    ushort* owT   = (ushort*)alloc((size_t)OUTW * HH * 2);
    ushort* MLH   = (ushort*)alloc((size_t)Mloc * HH * 2);
    ushort* TH1   = (ushort*)alloc((size_t)Mloc * 256 * 2);
    ushort* TH    = (ushort*)alloc((size_t)Mloc * HH * 2);
    ushort* RNN   = MLH;

    hipMemsetAsync(hRing, 0, (size_t)9 * BH * 2, stream);
    hipMemsetAsync(hLo, 0, (size_t)BH * 2, stream);
    hipMemsetAsync(c, 0, (size_t)BH * 4, stream);

    build_whl<<<(int)(((size_t)NPAD * KH + 255) / 256), 256, 0, stream>>>(rw, WhiT, WloT);
    build_wxt<<<(int)(((size_t)NPAD * KXP + 255) / 256), 256, 0, stream>>>(kw, rw, WxT);
    build_bc<<<(NPAD + 255) / 256, 256, 0, stream>>>(kb, rb, bc);
    build_ctt<<<(int)(((size_t)HH * HH * CSW + 255) / 256), 256, 0, stream>>>(cw, ctT);
    build_swt<<<(256 * 1024 + 255) / 256, 256, 0, stream>>>(sw, sb, swT, sbP);
    build_rswt<<<(1024 * 256 + 255) / 256, 256, 0, stream>>>(rsw, rswT);
    build_owt<<<(OUTW * HH + 255) / 256, 256, 0, stream>>>(ow, owT);

    const int SPLIT_STRIDE = BB * NPAD;

    for (int tBase = 0; tBase < TT; tBase += TCH) {
        // ---- batched x-part for the chunk: xoX = XAc @ WxT ----
        build_xac<<<(int)(((size_t)Mloc * KXP + 255) / 256), 256, 0, stream>>>(
            x, tim, XAc, tBase, Mloc);
        mm_kernel<2, 2, 0, 0><<<dim3(33, Mloc / 128), 256, 0, stream>>>(
            XAc, nullptr, nullptr, WxT, nullptr, xoX, nullptr, nullptr, nullptr,
            0, KXP, KXP, NPAD, KXP, 0, RING, tBase);
        // ---- scan steps ----
        for (int t = tBase; t < tBase + TCH; ++t) {
            mm_kernel<2, 2, 1, 0><<<dim3(224), 256, 0, stream>>>(
                WloT, hRing, hLo, WhiT, nullptr, xoP, nullptr, nullptr, nullptr,
                SPLIT_STRIDE, 0, KH, NPAD, KH, t, RING, 0);
            step_kernel<<<BB, 256, 0, stream>>>(
                xoP, xoX, bc, c, hRing, hLo, dist, t, tBase, RING);
        }
        // ---- batched phase-2 ----
        ld_chunk_kernel<<<(Mloc + 255) / 256, 256, 0, stream>>>(dist, ldC, tBase, Mloc);
        mlh_kernel<<<Mloc / 2, 256, 0, stream>>>(hRing, ldC, MLH, tBase, RING);
        mm_kernel<2, 2, 0, 1><<<dim3(2, Mloc / 128), 256, 0, stream>>>(
            MLH, nullptr, nullptr, swT, sbP, TH1, nullptr, nullptr, nullptr,
            0, 1024, 1024, 256, 1024, 0, RING, tBase);
        mm_kernel<2, 2, 0, 2><<<dim3(8, Mloc / 128), 256, 0, stream>>>(
            TH1, nullptr, nullptr, rswT, rsb, TH, nullptr, nullptr, nullptr,
            0, 256, 256, 1024, 256, 0, RING, tBase);
        // conv: m-tile-pinned 1-D grid, nM passed via t
        mm_kernel<2, 2, 2, 3><<<dim3(((nM + 7) / 8) * 64), 256, 0, stream>>>(
            nullptr, hRing, nullptr, ctT, cb, RNN, ldC, TH, nullptr,
            0, 0, HH * CSW, 1024, HH * CSW, nM, RING, tBase);
        mm_kernel<4, 1, 0, 4><<<dim3(1, Mloc / 256), 256, 0, stream>>>(
            RNN, nullptr, nullptr, owT, ob, nullptr, nullptr, nullptr, out,
            0, 1024, 1024, 0, 1024, 0, RING, tBase);
    }
}